// Round 1
// baseline (794.115 us; speedup 1.0000x reference)
//
#include <hip/hip_runtime.h>
#include <cstdint>
#include <cstddef>

// Problem constants (fixed by the reference)
#define H_DIM 1024
#define I_DIM 4096
#define E_NUM 8
#define TOPK  2
#define T_NUM 4096                 // B*S = 2*2048
#define NROWS (T_NUM * TOPK)       // 8192 assignment rows
#define BK    32                   // K-step in f16 elems: 64 B/row = 4x 16B chunks, XOR-swizzled

typedef _Float16 half8 __attribute__((ext_vector_type(8)));
typedef float    f32x4 __attribute__((ext_vector_type(4)));

// Async global->LDS, 16 B per lane. LDS dest: wave-uniform base + lane*16 (HW rule).
// Global side is per-lane -> supports gathered rows AND source-chunk swizzle.
__device__ __forceinline__ void async_copy16(void* lds, const void* g)
{
    __builtin_amdgcn_global_load_lds(
        (__attribute__((address_space(1))) unsigned int*)g,
        (__attribute__((address_space(3))) unsigned int*)lds,
        16 /*bytes*/, 0 /*offset*/, 0 /*aux*/);
}

// Swizzle (BK=32, 64 B rows): tile row t, chunk-pos p holds global chunk p ^ f(t),
//   f(t) = (t&3) ^ ((t>>2)&3).
// Staging instr covers 16 aligned rows: lane = rl*4 + c -> row rl, pos c; fetch global
//   chunk c ^ f(rl). Fragment read: row fm's K-chunk kq lives at pos kq ^ f(fm).
// Bank quads: every bank-quad gets exactly 2 of 16 lanes -> 2-way = free (m136).

// ---------------- fused fp32 -> fp16 conversion (x + 3 weight tensors) ----------------
#define NX4 (T_NUM * H_DIM / 4)
#define NW4 (E_NUM * I_DIM * H_DIM / 4)
__global__ void cvt_all(const float* __restrict__ x,  const float* __restrict__ gp,
                        const float* __restrict__ up, const float* __restrict__ dp,
                        _Float16* __restrict__ xh, _Float16* __restrict__ wg,
                        _Float16* __restrict__ wu, _Float16* __restrict__ wd)
{
    int i = blockIdx.x * blockDim.x + threadIdx.x;
    const int total = NX4 + 3 * NW4;
    if (i >= total) return;
    const float* s; _Float16* d; int j;
    if (i < NX4)              { s = x;  d = xh; j = i; }
    else if (i < NX4 + NW4)   { s = gp; d = wg; j = i - NX4; }
    else if (i < NX4 + 2*NW4) { s = up; d = wu; j = i - NX4 - NW4; }
    else                      { s = dp; d = wd; j = i - NX4 - 2*NW4; }
    float4 v = reinterpret_cast<const float4*>(s)[j];
    union { _Float16 h[4]; unsigned long long u; } o;
    o.h[0] = (_Float16)v.x; o.h[1] = (_Float16)v.y;
    o.h[2] = (_Float16)v.z; o.h[3] = (_Float16)v.w;
    reinterpret_cast<unsigned long long*>(d)[j] = o.u;
}

// ---------------- routing: count + prefix + scatter in one block ----------------
__global__ void route_all(const int* __restrict__ ei, const float* __restrict__ ew,
                          int* __restrict__ offs,
                          int* __restrict__ token_of_row, float* __restrict__ weight_of_row)
{
    __shared__ int cnt[E_NUM];
    __shared__ int cur[E_NUM];
    const int t = (int)threadIdx.x;
    if (t < E_NUM) cnt[t] = 0;
    __syncthreads();
    for (int s = t; s < NROWS; s += (int)blockDim.x) atomicAdd(&cnt[ei[s]], 1);
    __syncthreads();
    if (t == 0) {
        int acc = 0;
        for (int e = 0; e < E_NUM; ++e) { offs[e] = acc; cur[e] = acc; acc += cnt[e]; }
        offs[E_NUM] = acc;  // == NROWS
    }
    __syncthreads();
    for (int s = t; s < NROWS; s += (int)blockDim.x) {
        int e = ei[s];
        int r = atomicAdd(&cur[e], 1);
        token_of_row[r]  = s >> 1;   // TOPK = 2
        weight_of_row[r] = ew[s];
    }
}

// ---------------- fused gate+up grouped GEMM + SiLU*mul ----------------
// Tile: 128 rows x 64 cols of I, K = H = 1024, BK = 32. 4 waves (2x2); wave = 64x32 per matrix.
// Double-buffered LDS: stage tile kt+1 BEFORE computing tile kt; one barrier per K-step.
__global__ __launch_bounds__(256) void gateup_gemm(
    const _Float16* __restrict__ xh,      // [T][H]
    const _Float16* __restrict__ Wg,      // [E][I][H]
    const _Float16* __restrict__ Wu,      // [E][I][H]
    const int*      __restrict__ token_of_row,
    const int*      __restrict__ offs,
    _Float16*       __restrict__ inter)   // [NROWS][I]
{
    const int e = blockIdx.z;
    const int seg_start = offs[e], seg_end = offs[e + 1];
    const int m0 = seg_start + (int)blockIdx.y * 128;
    if (m0 >= seg_end) return;
    const int n0 = (int)blockIdx.x * 64;

    __shared__ _Float16 Ash[2][128 * BK];   // 2 x 8 KB
    __shared__ _Float16 Bgs[2][64 * BK];    // 2 x 4 KB
    __shared__ _Float16 Bus[2][64 * BK];    // 2 x 4 KB  -> 32 KB total, 5 blocks/CU

    const int tid  = (int)threadIdx.x;
    const int lane = tid & 63, wid = tid >> 6;
    const int wm = wid >> 1, wn = wid & 1;

    const int c   = lane & 3;                 // chunk position (16B) in 64B row
    const int rl  = lane >> 2;                // row within 16-row staging group
    const int frl = (rl & 3) ^ (rl >> 2);     // f(t) for staging
    const int gc  = c ^ frl;                  // swizzled global chunk to fetch

    // A staging: 8 instrs of 16 rows; this wave does q = 2*wid, 2*wid+1
    const _Float16* pA[2];
    int offA[2];
#pragma unroll
    for (int j = 0; j < 2; ++j) {
        int q = 2 * wid + j;
        int r = m0 + q * 16 + rl;
        if (r > seg_end - 1) r = seg_end - 1;       // clamp; garbage rows never stored
        int tok = token_of_row[r];
        pA[j] = xh + (size_t)tok * H_DIM + gc * 8;
        offA[j] = q * 16 * BK;
    }
    // B staging: 4 instrs each (64 rows); this wave does q = wid
    const int brow = wid * 16 + rl;
    const _Float16* pBg = Wg + ((size_t)e * I_DIM + n0 + brow) * H_DIM + gc * 8;
    const _Float16* pBu = Wu + ((size_t)e * I_DIM + n0 + brow) * H_DIM + gc * 8;
    const int offB = wid * 16 * BK;

    f32x4 accg[4][2], accu[4][2];
#pragma unroll
    for (int i = 0; i < 4; ++i)
#pragma unroll
        for (int j = 0; j < 2; ++j) {
            accg[i][j] = (f32x4){0.f, 0.f, 0.f, 0.f};
            accu[i][j] = (f32x4){0.f, 0.f, 0.f, 0.f};
        }

    const int fm = lane & 15, kq = lane >> 4;       // kq = 16B K-chunk index (0..3)
    const int fsw = (fm & 3) ^ ((fm >> 2) & 3);     // f(t) for fragment rows
    const int rdo = (kq ^ fsw) * 8;                 // swizzled element offset within row

    auto stage = [&](int buf, int ko) {
        async_copy16(&Ash[buf][offA[0]], pA[0] + ko);
        async_copy16(&Ash[buf][offA[1]], pA[1] + ko);
        async_copy16(&Bgs[buf][offB],    pBg   + ko);
        async_copy16(&Bus[buf][offB],    pBu   + ko);
    };
    auto compute = [&](int buf) {
        half8 a[4], bg[2], bu[2];
#pragma unroll
        for (int i = 0; i < 4; ++i)
            a[i] = *(const half8*)&Ash[buf][(wm * 64 + i * 16 + fm) * BK + rdo];
#pragma unroll
        for (int j = 0; j < 2; ++j) {
            bg[j] = *(const half8*)&Bgs[buf][(wn * 32 + j * 16 + fm) * BK + rdo];
            bu[j] = *(const half8*)&Bus[buf][(wn * 32 + j * 16 + fm) * BK + rdo];
        }
#pragma unroll
        for (int i = 0; i < 4; ++i)
#pragma unroll
            for (int j = 0; j < 2; ++j) {
                accg[i][j] = __builtin_amdgcn_mfma_f32_16x16x32_f16(a[i], bg[j], accg[i][j], 0, 0, 0);
                accu[i][j] = __builtin_amdgcn_mfma_f32_16x16x32_f16(a[i], bu[j], accu[i][j], 0, 0, 0);
            }
    };

    // Prologue: stage tile 0; drain; barrier (syncthreads = vmcnt(0)+lgkmcnt(0)+s_barrier).
    stage(0, 0);
    __syncthreads();

    constexpr int NK = H_DIM / BK;   // 32, even
    for (int kt = 0; kt < NK; kt += 2) {
        // prefetch kt+1 into buf1 while computing buf0; loads drained by the syncthreads
        // AFTER the MFMA phase -> latency hidden under compute + co-resident blocks.
        stage(1, (kt + 1) * BK);     // kt+1 <= NK-1 always inside loop
        compute(0);
        __syncthreads();
        if (kt + 2 < NK) stage(0, (kt + 2) * BK);
        compute(1);
        __syncthreads();
    }

    // Epilogue: inter = silu(g) * u, f16 store. C/D: col=lane&15, row=(lane>>4)*4+reg.
#pragma unroll
    for (int i = 0; i < 4; ++i) {
#pragma unroll
        for (int reg = 0; reg < 4; ++reg) {
            int r = m0 + wm * 64 + i * 16 + kq * 4 + reg;
            if (r < seg_end) {
#pragma unroll
                for (int j = 0; j < 2; ++j) {
                    int col = n0 + wn * 32 + j * 16 + fm;
                    float g = accg[i][j][reg];
                    float u = accu[i][j][reg];
                    float sv = (g / (1.f + __expf(-g))) * u;
                    inter[(size_t)r * I_DIM + col] = (_Float16)sv;
                }
            }
        }
    }
}

// ---------------- down grouped GEMM, weighted atomic scatter-add ----------------
// Tile: 128 rows x 128 cols of H, K = I = 4096, BK = 32. Wave = 64x64, acc[4][4].
// Same double-buffered prefetch structure.
__global__ __launch_bounds__(256) void down_gemm(
    const _Float16* __restrict__ inter,   // [NROWS][I]
    const _Float16* __restrict__ Wd,      // [E][H][I]
    const int*      __restrict__ token_of_row,
    const float*    __restrict__ weight_of_row,
    const int*      __restrict__ offs,
    float*          __restrict__ out)     // [T][H], pre-zeroed
{
    const int e = blockIdx.z;
    const int seg_start = offs[e], seg_end = offs[e + 1];
    const int m0 = seg_start + (int)blockIdx.y * 128;
    if (m0 >= seg_end) return;
    const int n0 = (int)blockIdx.x * 128;

    __shared__ _Float16 Ash[2][128 * BK];   // 2 x 8 KB
    __shared__ _Float16 Bsh[2][128 * BK];   // 2 x 8 KB -> 32 KB total

    const int tid  = (int)threadIdx.x;
    const int lane = tid & 63, wid = tid >> 6;
    const int wm = wid >> 1, wn = wid & 1;
    const int c   = lane & 3;
    const int rl  = lane >> 2;
    const int frl = (rl & 3) ^ (rl >> 2);
    const int gc  = c ^ frl;

    const _Float16* pA[2]; int offAB[2];
    const _Float16* pB[2];
#pragma unroll
    for (int j = 0; j < 2; ++j) {
        int q = 2 * wid + j;
        int row_in = q * 16 + rl;
        int r = m0 + row_in;
        if (r > seg_end - 1) r = seg_end - 1;
        pA[j] = inter + (size_t)r * I_DIM + gc * 8;
        offAB[j] = q * 16 * BK;
        int n = n0 + row_in;
        pB[j] = Wd + ((size_t)e * H_DIM + n) * I_DIM + gc * 8;
    }

    f32x4 acc[4][4];
#pragma unroll
    for (int i = 0; i < 4; ++i)
#pragma unroll
        for (int j = 0; j < 4; ++j) acc[i][j] = (f32x4){0.f, 0.f, 0.f, 0.f};

    const int fm = lane & 15, kq = lane >> 4;
    const int fsw = (fm & 3) ^ ((fm >> 2) & 3);
    const int rdo = (kq ^ fsw) * 8;

    auto stage = [&](int buf, int ko) {
        async_copy16(&Ash[buf][offAB[0]], pA[0] + ko);
        async_copy16(&Ash[buf][offAB[1]], pA[1] + ko);
        async_copy16(&Bsh[buf][offAB[0]], pB[0] + ko);
        async_copy16(&Bsh[buf][offAB[1]], pB[1] + ko);
    };
    auto compute = [&](int buf) {
        half8 a[4], b[4];
#pragma unroll
        for (int i = 0; i < 4; ++i)
            a[i] = *(const half8*)&Ash[buf][(wm * 64 + i * 16 + fm) * BK + rdo];
#pragma unroll
        for (int j = 0; j < 4; ++j)
            b[j] = *(const half8*)&Bsh[buf][(wn * 64 + j * 16 + fm) * BK + rdo];
#pragma unroll
        for (int i = 0; i < 4; ++i)
#pragma unroll
            for (int j = 0; j < 4; ++j)
                acc[i][j] = __builtin_amdgcn_mfma_f32_16x16x32_f16(a[i], b[j], acc[i][j], 0, 0, 0);
    };

    stage(0, 0);
    __syncthreads();

    constexpr int NK = I_DIM / BK;   // 128, even
    for (int kt = 0; kt < NK; kt += 2) {
        stage(1, (kt + 1) * BK);
        compute(0);
        __syncthreads();
        if (kt + 2 < NK) stage(0, (kt + 2) * BK);
        compute(1);
        __syncthreads();
    }

#pragma unroll
    for (int i = 0; i < 4; ++i) {
#pragma unroll
        for (int reg = 0; reg < 4; ++reg) {
            int r = m0 + wm * 64 + i * 16 + kq * 4 + reg;
            if (r < seg_end) {
                float w = weight_of_row[r];
                int   t = token_of_row[r];
#pragma unroll
                for (int j = 0; j < 4; ++j) {
                    int col = n0 + wn * 64 + j * 16 + fm;
                    atomicAdd(&out[(size_t)t * H_DIM + col], w * acc[i][j][reg]);
                }
            }
        }
    }
}

// ---------------- launch ----------------
extern "C" void kernel_launch(void* const* d_in, const int* in_sizes, int n_in,
                              void* d_out, int out_size, void* d_ws, size_t ws_size,
                              hipStream_t stream)
{
    const float* x  = (const float*)d_in[0];
    const int*   ei = (const int*)  d_in[1];
    const float* ew = (const float*)d_in[2];
    const float* gp = (const float*)d_in[3];
    const float* up = (const float*)d_in[4];
    const float* dp = (const float*)d_in[5];
    float* out = (float*)d_out;

    char* ws = (char*)d_ws;
    size_t o = 0;
    _Float16* xh    = (_Float16*)(ws + o); o += (size_t)T_NUM * H_DIM * 2;           // 8 MB
    _Float16* Wg_h  = (_Float16*)(ws + o); o += (size_t)E_NUM * I_DIM * H_DIM * 2;   // 64 MB
    _Float16* Wu_h  = (_Float16*)(ws + o); o += (size_t)E_NUM * I_DIM * H_DIM * 2;
    _Float16* Wd_h  = (_Float16*)(ws + o); o += (size_t)E_NUM * I_DIM * H_DIM * 2;
    _Float16* inter = (_Float16*)(ws + o); o += (size_t)NROWS * I_DIM * 2;           // 64 MB
    int*   offs          = (int*)  (ws + o);
    int*   token_of_row  = (int*)  (ws + o + 256);
    float* weight_of_row = (float*)(ws + o + 256 + (size_t)NROWS * 4);
    size_t ws_need = o + 256 + (size_t)NROWS * 8;
    if (ws_size < ws_need) return;  // diagnostic: absmax will equal |ref|max (~2.16)

    hipMemsetAsync(d_out, 0, (size_t)out_size * sizeof(float), stream);

    const int nt = 256;
    const int ncvt = NX4 + 3 * NW4;
    cvt_all<<<(ncvt + nt - 1) / nt, nt, 0, stream>>>(x, gp, up, dp, xh, Wg_h, Wu_h, Wd_h);

    route_all<<<1, 1024, 0, stream>>>(ei, ew, offs, token_of_row, weight_of_row);

    gateup_gemm<<<dim3(I_DIM / 64, NROWS / 128, E_NUM), 256, 0, stream>>>(
        xh, Wg_h, Wu_h, token_of_row, offs, inter);
    down_gemm<<<dim3(H_DIM / 128, NROWS / 128, E_NUM), 256, 0, stream>>>(
        inter, Wd_h, token_of_row, weight_of_row, offs, out);
}

// Round 3
// 740.651 us; speedup vs baseline: 1.0722x; 1.0722x over previous
//
#include <hip/hip_runtime.h>
#include <cstdint>
#include <cstddef>

// Problem constants (fixed by the reference)
#define H_DIM 1024
#define I_DIM 4096
#define E_NUM 8
#define TOPK  2
#define T_NUM 4096                 // B*S = 2*2048
#define NROWS (T_NUM * TOPK)       // 8192 assignment rows
#define BK    32                   // K-step in f16 elems: 64 B/row = 4x 16B chunks, XOR-swizzled

typedef _Float16 half8 __attribute__((ext_vector_type(8)));
typedef float    f32x4 __attribute__((ext_vector_type(4)));

// Async global->LDS, 16 B per lane. LDS dest: wave-uniform base + lane*16 (HW rule).
// Global side is per-lane -> supports gathered rows AND source-chunk swizzle.
__device__ __forceinline__ void async_copy16(void* lds, const void* g)
{
    __builtin_amdgcn_global_load_lds(
        (__attribute__((address_space(1))) unsigned int*)g,
        (__attribute__((address_space(3))) unsigned int*)lds,
        16 /*bytes*/, 0 /*offset*/, 0 /*aux*/);
}

// Swizzle (BK=32, 64 B rows): tile row t, chunk-pos p holds global chunk p ^ f(t),
//   f(t) = (t&3) ^ ((t>>2)&3).
// Staging instr covers 16 aligned rows: lane = rl*4 + c -> row rl, pos c; fetch global
//   chunk c ^ f(rl). Fragment read: row fm's K-chunk kq lives at pos kq ^ f(fm).
// Bank quads: every bank-quad gets exactly 2 of 16 lanes -> 2-way = free (m136).

// ---------------- fused fp32 -> fp16 conversion (x + 3 weight tensors) ----------------
#define NX4 (T_NUM * H_DIM / 4)
#define NW4 (E_NUM * I_DIM * H_DIM / 4)
__global__ void cvt_all(const float* __restrict__ x,  const float* __restrict__ gp,
                        const float* __restrict__ up, const float* __restrict__ dp,
                        _Float16* __restrict__ xh, _Float16* __restrict__ wg,
                        _Float16* __restrict__ wu, _Float16* __restrict__ wd)
{
    int i = blockIdx.x * blockDim.x + threadIdx.x;
    const int total = NX4 + 3 * NW4;
    if (i >= total) return;
    const float* s; _Float16* d; int j;
    if (i < NX4)              { s = x;  d = xh; j = i; }
    else if (i < NX4 + NW4)   { s = gp; d = wg; j = i - NX4; }
    else if (i < NX4 + 2*NW4) { s = up; d = wu; j = i - NX4 - NW4; }
    else                      { s = dp; d = wd; j = i - NX4 - 2*NW4; }
    float4 v = reinterpret_cast<const float4*>(s)[j];
    union { _Float16 h[4]; unsigned long long u; } o;
    o.h[0] = (_Float16)v.x; o.h[1] = (_Float16)v.y;
    o.h[2] = (_Float16)v.z; o.h[3] = (_Float16)v.w;
    reinterpret_cast<unsigned long long*>(d)[j] = o.u;
}

// ---------------- routing: count + prefix + scatter in one block ----------------
__global__ void route_all(const int* __restrict__ ei, const float* __restrict__ ew,
                          int* __restrict__ offs,
                          int* __restrict__ token_of_row, float* __restrict__ weight_of_row)
{
    __shared__ int cnt[E_NUM];
    __shared__ int cur[E_NUM];
    const int t = (int)threadIdx.x;
    if (t < E_NUM) cnt[t] = 0;
    __syncthreads();
    for (int s = t; s < NROWS; s += (int)blockDim.x) atomicAdd(&cnt[ei[s]], 1);
    __syncthreads();
    if (t == 0) {
        int acc = 0;
        for (int e = 0; e < E_NUM; ++e) { offs[e] = acc; cur[e] = acc; acc += cnt[e]; }
        offs[E_NUM] = acc;  // == NROWS
    }
    __syncthreads();
    for (int s = t; s < NROWS; s += (int)blockDim.x) {
        int e = ei[s];
        int r = atomicAdd(&cur[e], 1);
        token_of_row[r]  = s >> 1;   // TOPK = 2
        weight_of_row[r] = ew[s];
    }
}

// ---------------- fused gate+up grouped GEMM + SiLU*mul ----------------
// Tile: 128 rows x 64 cols of I, K = H = 1024, BK = 32. 4 waves (2x2); wave = 64x32 per matrix.
// Single-buffer LDS (16 KB -> 8 blocks/CU), but K-step reordered so the global_load_lds
// drain sits AFTER the MFMA cluster: ds_read frags -> barrier (tile dead) -> issue next
// tile's loads -> MFMA (reg-only, covers load latency) -> barrier/drain.
__global__ __launch_bounds__(256) void gateup_gemm(
    const _Float16* __restrict__ xh,      // [T][H]
    const _Float16* __restrict__ Wg,      // [E][I][H]
    const _Float16* __restrict__ Wu,      // [E][I][H]
    const int*      __restrict__ token_of_row,
    const int*      __restrict__ offs,
    _Float16*       __restrict__ inter)   // [NROWS][I]
{
    const int e = blockIdx.z;
    const int seg_start = offs[e], seg_end = offs[e + 1];
    const int m0 = seg_start + (int)blockIdx.y * 128;
    if (m0 >= seg_end) return;
    const int n0 = (int)blockIdx.x * 64;

    __shared__ _Float16 Ash[128 * BK];   // 8 KB
    __shared__ _Float16 Bgs[64 * BK];    // 4 KB
    __shared__ _Float16 Bus[64 * BK];    // 4 KB

    const int tid  = (int)threadIdx.x;
    const int lane = tid & 63, wid = tid >> 6;
    const int wm = wid >> 1, wn = wid & 1;

    const int c   = lane & 3;                 // chunk position (16B) in 64B row
    const int rl  = lane >> 2;                // row within 16-row staging group
    const int frl = (rl & 3) ^ (rl >> 2);     // f(t) for staging
    const int gc  = c ^ frl;                  // swizzled global chunk to fetch

    // A staging: 8 instrs of 16 rows; this wave does q = 2*wid, 2*wid+1
    const _Float16* pA[2];
    _Float16* lA[2];
#pragma unroll
    for (int j = 0; j < 2; ++j) {
        int q = 2 * wid + j;
        int r = m0 + q * 16 + rl;
        if (r > seg_end - 1) r = seg_end - 1;       // clamp; garbage rows never stored
        int tok = token_of_row[r];
        pA[j] = xh + (size_t)tok * H_DIM + gc * 8;
        lA[j] = &Ash[q * 16 * BK];
    }
    // B staging: 4 instrs each (64 rows); this wave does q = wid
    const int brow = wid * 16 + rl;
    const _Float16* pBg = Wg + ((size_t)e * I_DIM + n0 + brow) * H_DIM + gc * 8;
    const _Float16* pBu = Wu + ((size_t)e * I_DIM + n0 + brow) * H_DIM + gc * 8;
    _Float16* lBg = &Bgs[wid * 16 * BK];
    _Float16* lBu = &Bus[wid * 16 * BK];

    f32x4 accg[4][2], accu[4][2];
#pragma unroll
    for (int i = 0; i < 4; ++i)
#pragma unroll
        for (int j = 0; j < 2; ++j) {
            accg[i][j] = (f32x4){0.f, 0.f, 0.f, 0.f};
            accu[i][j] = (f32x4){0.f, 0.f, 0.f, 0.f};
        }

    const int fm = lane & 15, kq = lane >> 4;       // kq = 16B K-chunk index (0..3)
    const int fsw = (fm & 3) ^ ((fm >> 2) & 3);     // f(t) for fragment rows
    const int rdo = (kq ^ fsw) * 8;                 // swizzled element offset within row

    auto stage = [&](int ko) {
        async_copy16(lA[0], pA[0] + ko);
        async_copy16(lA[1], pA[1] + ko);
        async_copy16(lBg,   pBg   + ko);
        async_copy16(lBu,   pBu   + ko);
    };

    // Prologue: stage tile 0; syncthreads drains vmcnt(0) and makes it visible.
    stage(0);
    __syncthreads();

    constexpr int NK = H_DIM / BK;   // 32
    for (int kt = 0; kt < NK; ++kt) {
        // 1) fragments -> regs (tile kt)
        half8 a[4], bg[2], bu[2];
#pragma unroll
        for (int i = 0; i < 4; ++i)
            a[i] = *(const half8*)&Ash[(wm * 64 + i * 16 + fm) * BK + rdo];
#pragma unroll
        for (int j = 0; j < 2; ++j) {
            bg[j] = *(const half8*)&Bgs[(wn * 32 + j * 16 + fm) * BK + rdo];
            bu[j] = *(const half8*)&Bus[(wn * 32 + j * 16 + fm) * BK + rdo];
        }
        // 2) all waves done reading -> LDS tile is dead, safe to overwrite
        __syncthreads();
        // 3) issue next tile's loads NOW; they fly during the MFMA cluster
        if (kt + 1 < NK) stage((kt + 1) * BK);
        __builtin_amdgcn_sched_barrier(0);   // keep load-issue before the MFMAs
        // 4) register-only MFMA cluster — the latency-hiding window
#pragma unroll
        for (int i = 0; i < 4; ++i)
#pragma unroll
            for (int j = 0; j < 2; ++j) {
                accg[i][j] = __builtin_amdgcn_mfma_f32_16x16x32_f16(a[i], bg[j], accg[i][j], 0, 0, 0);
                accu[i][j] = __builtin_amdgcn_mfma_f32_16x16x32_f16(a[i], bu[j], accu[i][j], 0, 0, 0);
            }
        // 5) drain + visibility for tile kt+1
        __syncthreads();
    }

    // Epilogue: inter = silu(g) * u, f16 store. C/D: col=lane&15, row=(lane>>4)*4+reg.
#pragma unroll
    for (int i = 0; i < 4; ++i) {
#pragma unroll
        for (int reg = 0; reg < 4; ++reg) {
            int r = m0 + wm * 64 + i * 16 + kq * 4 + reg;
            if (r < seg_end) {
#pragma unroll
                for (int j = 0; j < 2; ++j) {
                    int col = n0 + wn * 32 + j * 16 + fm;
                    float g = accg[i][j][reg];
                    float u = accu[i][j][reg];
                    float sv = (g / (1.f + __expf(-g))) * u;
                    inter[(size_t)r * I_DIM + col] = (_Float16)sv;
                }
            }
        }
    }
}

// ---------------- down grouped GEMM, weighted atomic scatter-add ----------------
// Tile: 128 rows x 128 cols of H, K = I = 4096, BK = 32. Wave = 64x64, acc[4][4].
// Same reordered single-buffer K-step.
__global__ __launch_bounds__(256) void down_gemm(
    const _Float16* __restrict__ inter,   // [NROWS][I]
    const _Float16* __restrict__ Wd,      // [E][H][I]
    const int*      __restrict__ token_of_row,
    const float*    __restrict__ weight_of_row,
    const int*      __restrict__ offs,
    float*          __restrict__ out)     // [T][H], pre-zeroed
{
    const int e = blockIdx.z;
    const int seg_start = offs[e], seg_end = offs[e + 1];
    const int m0 = seg_start + (int)blockIdx.y * 128;
    if (m0 >= seg_end) return;
    const int n0 = (int)blockIdx.x * 128;

    __shared__ _Float16 Ash[128 * BK];   // 8 KB
    __shared__ _Float16 Bsh[128 * BK];   // 8 KB

    const int tid  = (int)threadIdx.x;
    const int lane = tid & 63, wid = tid >> 6;
    const int wm = wid >> 1, wn = wid & 1;
    const int c   = lane & 3;
    const int rl  = lane >> 2;
    const int frl = (rl & 3) ^ (rl >> 2);
    const int gc  = c ^ frl;

    const _Float16* pA[2]; _Float16* lA[2];
    const _Float16* pB[2]; _Float16* lB[2];
#pragma unroll
    for (int j = 0; j < 2; ++j) {
        int q = 2 * wid + j;
        int row_in = q * 16 + rl;
        int r = m0 + row_in;
        if (r > seg_end - 1) r = seg_end - 1;
        pA[j] = inter + (size_t)r * I_DIM + gc * 8;
        lA[j] = &Ash[q * 16 * BK];
        int n = n0 + row_in;
        pB[j] = Wd + ((size_t)e * H_DIM + n) * I_DIM + gc * 8;
        lB[j] = &Bsh[q * 16 * BK];
    }

    f32x4 acc[4][4];
#pragma unroll
    for (int i = 0; i < 4; ++i)
#pragma unroll
        for (int j = 0; j < 4; ++j) acc[i][j] = (f32x4){0.f, 0.f, 0.f, 0.f};

    const int fm = lane & 15, kq = lane >> 4;
    const int fsw = (fm & 3) ^ ((fm >> 2) & 3);
    const int rdo = (kq ^ fsw) * 8;

    auto stage = [&](int ko) {
        async_copy16(lA[0], pA[0] + ko);
        async_copy16(lA[1], pA[1] + ko);
        async_copy16(lB[0], pB[0] + ko);
        async_copy16(lB[1], pB[1] + ko);
    };

    stage(0);
    __syncthreads();

    constexpr int NK = I_DIM / BK;   // 128
    for (int kt = 0; kt < NK; ++kt) {
        half8 a[4], b[4];
#pragma unroll
        for (int i = 0; i < 4; ++i)
            a[i] = *(const half8*)&Ash[(wm * 64 + i * 16 + fm) * BK + rdo];
#pragma unroll
        for (int j = 0; j < 4; ++j)
            b[j] = *(const half8*)&Bsh[(wn * 64 + j * 16 + fm) * BK + rdo];
        __syncthreads();
        if (kt + 1 < NK) stage((kt + 1) * BK);
        __builtin_amdgcn_sched_barrier(0);
#pragma unroll
        for (int i = 0; i < 4; ++i)
#pragma unroll
            for (int j = 0; j < 4; ++j)
                acc[i][j] = __builtin_amdgcn_mfma_f32_16x16x32_f16(a[i], b[j], acc[i][j], 0, 0, 0);
        __syncthreads();
    }

#pragma unroll
    for (int i = 0; i < 4; ++i) {
#pragma unroll
        for (int reg = 0; reg < 4; ++reg) {
            int r = m0 + wm * 64 + i * 16 + kq * 4 + reg;
            if (r < seg_end) {
                float w = weight_of_row[r];
                int   t = token_of_row[r];
#pragma unroll
                for (int j = 0; j < 4; ++j) {
                    int col = n0 + wn * 64 + j * 16 + fm;
                    atomicAdd(&out[(size_t)t * H_DIM + col], w * acc[i][j][reg]);
                }
            }
        }
    }
}

// ---------------- launch ----------------
extern "C" void kernel_launch(void* const* d_in, const int* in_sizes, int n_in,
                              void* d_out, int out_size, void* d_ws, size_t ws_size,
                              hipStream_t stream)
{
    const float* x  = (const float*)d_in[0];
    const int*   ei = (const int*)  d_in[1];
    const float* ew = (const float*)d_in[2];
    const float* gp = (const float*)d_in[3];
    const float* up = (const float*)d_in[4];
    const float* dp = (const float*)d_in[5];
    float* out = (float*)d_out;

    char* ws = (char*)d_ws;
    size_t o = 0;
    _Float16* xh    = (_Float16*)(ws + o); o += (size_t)T_NUM * H_DIM * 2;           // 8 MB
    _Float16* Wg_h  = (_Float16*)(ws + o); o += (size_t)E_NUM * I_DIM * H_DIM * 2;   // 64 MB
    _Float16* Wu_h  = (_Float16*)(ws + o); o += (size_t)E_NUM * I_DIM * H_DIM * 2;
    _Float16* Wd_h  = (_Float16*)(ws + o); o += (size_t)E_NUM * I_DIM * H_DIM * 2;
    _Float16* inter = (_Float16*)(ws + o); o += (size_t)NROWS * I_DIM * 2;           // 64 MB
    int*   offs          = (int*)  (ws + o);
    int*   token_of_row  = (int*)  (ws + o + 256);
    float* weight_of_row = (float*)(ws + o + 256 + (size_t)NROWS * 4);
    size_t ws_need = o + 256 + (size_t)NROWS * 8;
    if (ws_size < ws_need) return;  // diagnostic: absmax will equal |ref|max (~2.16)

    hipMemsetAsync(d_out, 0, (size_t)out_size * sizeof(float), stream);

    const int nt = 256;
    const int ncvt = NX4 + 3 * NW4;
    cvt_all<<<(ncvt + nt - 1) / nt, nt, 0, stream>>>(x, gp, up, dp, xh, Wg_h, Wu_h, Wd_h);

    route_all<<<1, 1024, 0, stream>>>(ei, ew, offs, token_of_row, weight_of_row);

    gateup_gemm<<<dim3(I_DIM / 64, NROWS / 128, E_NUM), 256, 0, stream>>>(
        xh, Wg_h, Wu_h, token_of_row, offs, inter);
    down_gemm<<<dim3(H_DIM / 128, NROWS / 128, E_NUM), 256, 0, stream>>>(
        inter, Wd_h, token_of_row, weight_of_row, offs, out);
}

// Round 6
// 685.900 us; speedup vs baseline: 1.1578x; 1.0798x over previous
//
#include <hip/hip_runtime.h>
#include <cstdint>
#include <cstddef>

// Problem constants (fixed by the reference)
#define H_DIM 1024
#define I_DIM 4096
#define E_NUM 8
#define TOPK  2
#define T_NUM 4096                 // B*S = 2*2048
#define NROWS (T_NUM * TOPK)       // 8192 assignment rows
#define BK    64                   // K-step in f16 elems: 128 B/row = 8x 16B chunks, XOR-swizzled

typedef _Float16 half8 __attribute__((ext_vector_type(8)));
typedef float    f32x4 __attribute__((ext_vector_type(4)));

// Async global->LDS, 16 B per lane. LDS dest: wave-uniform base + lane*16 (HW rule).
// Global side is per-lane -> supports gathered rows AND source-chunk swizzle.
__device__ __forceinline__ void async_copy16(void* lds, const void* g)
{
    __builtin_amdgcn_global_load_lds(
        (__attribute__((address_space(1))) unsigned int*)g,
        (__attribute__((address_space(3))) unsigned int*)lds,
        16 /*bytes*/, 0 /*offset*/, 0 /*aux*/);
}

// Swizzle (BK=64, 128 B rows, 8 chunks of 16 B): tile row t, chunk-pos p holds global
// chunk p ^ (t&7).
// Staging instr covers 8 rows (64 lanes x 16B = 1KB): lane = r8*8 + c8 -> row r8,
//   pos c8; fetch global chunk c8 ^ r8 (row groups are 8-aligned, so (row&7)==r8).
//   Each 8-lane group covers one full 128B row segment (permuted within) -> coalesced.
// Fragment read: row fm, k-half h, 16B chunk kq: position ((h<<2)|kq) ^ (fm&7).
//   16 lanes of a group land on all 8 bank-quads evenly -> minimal aliasing (free).

// ---------------- fused fp32 -> fp16 conversion (x + 3 weight tensors) ----------------
#define NX4 (T_NUM * H_DIM / 4)
#define NW4 (E_NUM * I_DIM * H_DIM / 4)
__global__ void cvt_all(const float* __restrict__ x,  const float* __restrict__ gp,
                        const float* __restrict__ up, const float* __restrict__ dp,
                        _Float16* __restrict__ xh, _Float16* __restrict__ wg,
                        _Float16* __restrict__ wu, _Float16* __restrict__ wd)
{
    int i = blockIdx.x * blockDim.x + threadIdx.x;
    const int total = NX4 + 3 * NW4;
    if (i >= total) return;
    const float* s; _Float16* d; int j;
    if (i < NX4)              { s = x;  d = xh; j = i; }
    else if (i < NX4 + NW4)   { s = gp; d = wg; j = i - NX4; }
    else if (i < NX4 + 2*NW4) { s = up; d = wu; j = i - NX4 - NW4; }
    else                      { s = dp; d = wd; j = i - NX4 - 2*NW4; }
    float4 v = reinterpret_cast<const float4*>(s)[j];
    union { _Float16 h[4]; unsigned long long u; } o;
    o.h[0] = (_Float16)v.x; o.h[1] = (_Float16)v.y;
    o.h[2] = (_Float16)v.z; o.h[3] = (_Float16)v.w;
    reinterpret_cast<unsigned long long*>(d)[j] = o.u;
}

// ---------------- routing: count + prefix + scatter in one block ----------------
__global__ void route_all(const int* __restrict__ ei, const float* __restrict__ ew,
                          int* __restrict__ offs,
                          int* __restrict__ token_of_row, float* __restrict__ weight_of_row)
{
    __shared__ int cnt[E_NUM];
    __shared__ int cur[E_NUM];
    const int t = (int)threadIdx.x;
    if (t < E_NUM) cnt[t] = 0;
    __syncthreads();
    for (int s = t; s < NROWS; s += (int)blockDim.x) atomicAdd(&cnt[ei[s]], 1);
    __syncthreads();
    if (t == 0) {
        int acc = 0;
        for (int e = 0; e < E_NUM; ++e) { offs[e] = acc; cur[e] = acc; acc += cnt[e]; }
        offs[E_NUM] = acc;  // == NROWS
    }
    __syncthreads();
    for (int s = t; s < NROWS; s += (int)blockDim.x) {
        int e = ei[s];
        int r = atomicAdd(&cur[e], 1);
        token_of_row[r]  = s >> 1;   // TOPK = 2
        weight_of_row[r] = ew[s];
    }
}

// ---------------- fused gate+up grouped GEMM + SiLU*mul ----------------
// Tile: 128 rows x 64 cols of I (per matrix), K = H = 1024, BK = 64 (m97 config).
// 4 waves (2x2); wave = 64x32 per matrix. 32 MFMA per barrier-pair (2x the BK=32 version).
// Plain 2-barrier loop: sync -> stage -> sync -> compute. No sched_barrier (m141).
__global__ __launch_bounds__(256, 3) void gateup_gemm(
    const _Float16* __restrict__ xh,      // [T][H]
    const _Float16* __restrict__ Wg,      // [E][I][H]
    const _Float16* __restrict__ Wu,      // [E][I][H]
    const int*      __restrict__ token_of_row,
    const int*      __restrict__ offs,
    _Float16*       __restrict__ inter)   // [NROWS][I]
{
    const int e = blockIdx.z;
    const int seg_start = offs[e], seg_end = offs[e + 1];
    const int m0 = seg_start + (int)blockIdx.y * 128;
    if (m0 >= seg_end) return;
    const int n0 = (int)blockIdx.x * 64;

    __shared__ _Float16 Ash[128 * BK];   // 16 KB
    __shared__ _Float16 Bgs[64 * BK];    // 8 KB
    __shared__ _Float16 Bus[64 * BK];    // 8 KB  -> 32 KB total

    const int tid  = (int)threadIdx.x;
    const int lane = tid & 63, wid = tid >> 6;
    const int wm = wid >> 1, wn = wid & 1;

    const int r8 = lane >> 3;                 // row within 8-row staging group (0..7)
    const int c8 = lane & 7;                  // chunk position (16B) in 128B row (0..7)
    const int gc = c8 ^ r8;                   // swizzled global chunk to fetch

    // A staging: 16 instrs of 8 rows; this wave does q = 4*wid .. 4*wid+3
    const _Float16* pA[4];
    _Float16* lA[4];
#pragma unroll
    for (int j = 0; j < 4; ++j) {
        int q = 4 * wid + j;                  // 0..15
        int r = m0 + q * 8 + r8;              // 0..127 within tile
        if (r > seg_end - 1) r = seg_end - 1; // clamp; garbage rows never stored
        int tok = token_of_row[r];
        pA[j] = xh + (size_t)tok * H_DIM + gc * 8;
        lA[j] = &Ash[q * 8 * BK];
    }
    // B staging: 8 instrs each (64 rows); this wave does q = 2*wid, 2*wid+1
    const _Float16* pBg[2]; const _Float16* pBu[2];
    _Float16* lBg[2]; _Float16* lBu[2];
#pragma unroll
    for (int j = 0; j < 2; ++j) {
        int q = 2 * wid + j;                  // 0..7
        int row = q * 8 + r8;                 // 0..63
        pBg[j] = Wg + ((size_t)e * I_DIM + n0 + row) * H_DIM + gc * 8;
        pBu[j] = Wu + ((size_t)e * I_DIM + n0 + row) * H_DIM + gc * 8;
        lBg[j] = &Bgs[q * 8 * BK];
        lBu[j] = &Bus[q * 8 * BK];
    }

    f32x4 accg[4][2], accu[4][2];
#pragma unroll
    for (int i = 0; i < 4; ++i)
#pragma unroll
        for (int j = 0; j < 2; ++j) {
            accg[i][j] = (f32x4){0.f, 0.f, 0.f, 0.f};
            accu[i][j] = (f32x4){0.f, 0.f, 0.f, 0.f};
        }

    const int fm = lane & 15, kq = lane >> 4;   // kq = 16B chunk within 32-elem k-slice
    const int f3 = fm & 7;                      // swizzle key for fragment rows

    constexpr int NK = H_DIM / BK;   // 16
    for (int kt = 0; kt < NK; ++kt) {
        const int ko = kt * BK;
        __syncthreads();                       // previous readers done -> LDS dead
#pragma unroll
        for (int j = 0; j < 4; ++j) async_copy16(lA[j], pA[j] + ko);
#pragma unroll
        for (int j = 0; j < 2; ++j) {
            async_copy16(lBg[j], pBg[j] + ko);
            async_copy16(lBu[j], pBu[j] + ko);
        }
        __syncthreads();                       // drain + visibility

#pragma unroll
        for (int h = 0; h < 2; ++h) {          // two 32-elem k-halves of the 64 tile
            const int rdo = (((h << 2) | kq) ^ f3) * 8;   // swizzled elem offset
            half8 a[4], bg[2], bu[2];
#pragma unroll
            for (int i = 0; i < 4; ++i)
                a[i] = *(const half8*)&Ash[(wm * 64 + i * 16 + fm) * BK + rdo];
#pragma unroll
            for (int j = 0; j < 2; ++j) {
                bg[j] = *(const half8*)&Bgs[(wn * 32 + j * 16 + fm) * BK + rdo];
                bu[j] = *(const half8*)&Bus[(wn * 32 + j * 16 + fm) * BK + rdo];
            }
#pragma unroll
            for (int i = 0; i < 4; ++i)
#pragma unroll
                for (int j = 0; j < 2; ++j) {
                    accg[i][j] = __builtin_amdgcn_mfma_f32_16x16x32_f16(a[i], bg[j], accg[i][j], 0, 0, 0);
                    accu[i][j] = __builtin_amdgcn_mfma_f32_16x16x32_f16(a[i], bu[j], accu[i][j], 0, 0, 0);
                }
        }
    }

    // Epilogue: inter = silu(g) * u, f16 store. C/D: col=lane&15, row=(lane>>4)*4+reg.
#pragma unroll
    for (int i = 0; i < 4; ++i) {
#pragma unroll
        for (int reg = 0; reg < 4; ++reg) {
            int r = m0 + wm * 64 + i * 16 + kq * 4 + reg;
            if (r < seg_end) {
#pragma unroll
                for (int j = 0; j < 2; ++j) {
                    int col = n0 + wn * 32 + j * 16 + fm;
                    float g = accg[i][j][reg];
                    float u = accu[i][j][reg];
                    float sv = (g / (1.f + __expf(-g))) * u;
                    inter[(size_t)r * I_DIM + col] = (_Float16)sv;
                }
            }
        }
    }
}

// ---------------- down grouped GEMM, weighted atomic scatter-add ----------------
// Tile: 128 rows x 128 cols of H, K = I = 4096, BK = 64. Wave = 64x64, acc[4][4].
// Structurally identical to m97's 912-TF kernel.
__global__ __launch_bounds__(256, 3) void down_gemm(
    const _Float16* __restrict__ inter,   // [NROWS][I]
    const _Float16* __restrict__ Wd,      // [E][H][I]
    const int*      __restrict__ token_of_row,
    const float*    __restrict__ weight_of_row,
    const int*      __restrict__ offs,
    float*          __restrict__ out)     // [T][H], pre-zeroed
{
    const int e = blockIdx.z;
    const int seg_start = offs[e], seg_end = offs[e + 1];
    const int m0 = seg_start + (int)blockIdx.y * 128;
    if (m0 >= seg_end) return;
    const int n0 = (int)blockIdx.x * 128;

    __shared__ _Float16 Ash[128 * BK];   // 16 KB
    __shared__ _Float16 Bsh[128 * BK];   // 16 KB -> 32 KB total

    const int tid  = (int)threadIdx.x;
    const int lane = tid & 63, wid = tid >> 6;
    const int wm = wid >> 1, wn = wid & 1;
    const int r8 = lane >> 3;
    const int c8 = lane & 7;
    const int gc = c8 ^ r8;

    // A and B each 16 instrs of 8 rows; this wave does q = 4*wid .. 4*wid+3
    const _Float16* pA[4]; _Float16* lA[4];
    const _Float16* pB[4]; _Float16* lB[4];
#pragma unroll
    for (int j = 0; j < 4; ++j) {
        int q = 4 * wid + j;                  // 0..15
        int row_in = q * 8 + r8;              // 0..127
        int r = m0 + row_in;
        if (r > seg_end - 1) r = seg_end - 1;
        pA[j] = inter + (size_t)r * I_DIM + gc * 8;
        lA[j] = &Ash[q * 8 * BK];
        int n = n0 + row_in;
        pB[j] = Wd + ((size_t)e * H_DIM + n) * I_DIM + gc * 8;
        lB[j] = &Bsh[q * 8 * BK];
    }

    f32x4 acc[4][4];
#pragma unroll
    for (int i = 0; i < 4; ++i)
#pragma unroll
        for (int j = 0; j < 4; ++j) acc[i][j] = (f32x4){0.f, 0.f, 0.f, 0.f};

    const int fm = lane & 15, kq = lane >> 4;
    const int f3 = fm & 7;

    constexpr int NK = I_DIM / BK;   // 64
    for (int kt = 0; kt < NK; ++kt) {
        const int ko = kt * BK;
        __syncthreads();
#pragma unroll
        for (int j = 0; j < 4; ++j) {
            async_copy16(lA[j], pA[j] + ko);
            async_copy16(lB[j], pB[j] + ko);
        }
        __syncthreads();

#pragma unroll
        for (int h = 0; h < 2; ++h) {
            const int rdo = (((h << 2) | kq) ^ f3) * 8;
            half8 a[4], b[4];
#pragma unroll
            for (int i = 0; i < 4; ++i)
                a[i] = *(const half8*)&Ash[(wm * 64 + i * 16 + fm) * BK + rdo];
#pragma unroll
            for (int j = 0; j < 4; ++j)
                b[j] = *(const half8*)&Bsh[(wn * 64 + j * 16 + fm) * BK + rdo];
#pragma unroll
            for (int i = 0; i < 4; ++i)
#pragma unroll
                for (int j = 0; j < 4; ++j)
                    acc[i][j] = __builtin_amdgcn_mfma_f32_16x16x32_f16(a[i], b[j], acc[i][j], 0, 0, 0);
        }
    }

#pragma unroll
    for (int i = 0; i < 4; ++i) {
#pragma unroll
        for (int reg = 0; reg < 4; ++reg) {
            int r = m0 + wm * 64 + i * 16 + kq * 4 + reg;
            if (r < seg_end) {
                float w = weight_of_row[r];
                int   t = token_of_row[r];
#pragma unroll
                for (int j = 0; j < 4; ++j) {
                    int col = n0 + wn * 64 + j * 16 + fm;
                    atomicAdd(&out[(size_t)t * H_DIM + col], w * acc[i][j][reg]);
                }
            }
        }
    }
}

// ---------------- launch ----------------
extern "C" void kernel_launch(void* const* d_in, const int* in_sizes, int n_in,
                              void* d_out, int out_size, void* d_ws, size_t ws_size,
                              hipStream_t stream)
{
    const float* x  = (const float*)d_in[0];
    const int*   ei = (const int*)  d_in[1];
    const float* ew = (const float*)d_in[2];
    const float* gp = (const float*)d_in[3];
    const float* up = (const float*)d_in[4];
    const float* dp = (const float*)d_in[5];
    float* out = (float*)d_out;

    char* ws = (char*)d_ws;
    size_t o = 0;
    _Float16* xh    = (_Float16*)(ws + o); o += (size_t)T_NUM * H_DIM * 2;           // 8 MB
    _Float16* Wg_h  = (_Float16*)(ws + o); o += (size_t)E_NUM * I_DIM * H_DIM * 2;   // 64 MB
    _Float16* Wu_h  = (_Float16*)(ws + o); o += (size_t)E_NUM * I_DIM * H_DIM * 2;
    _Float16* Wd_h  = (_Float16*)(ws + o); o += (size_t)E_NUM * I_DIM * H_DIM * 2;
    _Float16* inter = (_Float16*)(ws + o); o += (size_t)NROWS * I_DIM * 2;           // 64 MB
    int*   offs          = (int*)  (ws + o);
    int*   token_of_row  = (int*)  (ws + o + 256);
    float* weight_of_row = (float*)(ws + o + 256 + (size_t)NROWS * 4);
    size_t ws_need = o + 256 + (size_t)NROWS * 8;
    if (ws_size < ws_need) return;  // diagnostic: absmax will equal |ref|max (~2.16)

    hipMemsetAsync(d_out, 0, (size_t)out_size * sizeof(float), stream);

    const int nt = 256;
    const int ncvt = NX4 + 3 * NW4;
    cvt_all<<<(ncvt + nt - 1) / nt, nt, 0, stream>>>(x, gp, up, dp, xh, Wg_h, Wu_h, Wd_h);

    route_all<<<1, 1024, 0, stream>>>(ei, ew, offs, token_of_row, weight_of_row);

    gateup_gemm<<<dim3(I_DIM / 64, NROWS / 128, E_NUM), 256, 0, stream>>>(
        xh, Wg_h, Wu_h, token_of_row, offs, inter);
    down_gemm<<<dim3(H_DIM / 128, NROWS / 128, E_NUM), 256, 0, stream>>>(
        inter, Wd_h, token_of_row, weight_of_row, offs, out);
}